// Round 1
// baseline (630.555 us; speedup 1.0000x reference)
//
#include <hip/hip_runtime.h>
#include <cstddef>

#define NREL 8
#define NBASE 4

// ---------------------------------------------------------------------------
// Count edges per (dst, relation) segment. cnt must be zeroed beforehand.
// ---------------------------------------------------------------------------
__global__ __launch_bounds__(256) void count_kernel(const int* __restrict__ dst,
                                                    const int* __restrict__ et,
                                                    int* __restrict__ cnt, int E)
{
    int e = blockIdx.x * 256 + threadIdx.x;
    if (e < E) atomicAdd(&cnt[dst[e] * NREL + et[e]], 1);
}

// ---------------------------------------------------------------------------
// Generic small GEMM: out[n, c] = sum_k in[n,k] * W[k, c]  (+ bias[c])
//   K:       reduction dim (128 or 64)
//   M:       output cols (256 for basis part, 64 for root part)
//   LDIN:    row stride of input
//   LDOUT:   row stride of output
//   RELU_IN: apply relu when staging input rows (layer-2 reads relu(h1))
//   BASISW:  W is basis[B,K,64] viewed as [K, B*64] (k-stride 64 either way)
// One thread computes 8 consecutive output columns (two float4 W loads/iter).
// ---------------------------------------------------------------------------
template<int K, int M, int LDIN, int LDOUT, bool RELU_IN, bool HASBIAS, bool BASISW>
__global__ __launch_bounds__(256) void gemm8(const float* __restrict__ in,
                                             const float* __restrict__ W,
                                             const float* __restrict__ bias,
                                             float* __restrict__ out, int N)
{
    constexpr int TPR = M / 8;      // threads per row
    constexpr int RPB = 256 / TPR;  // rows per block
    __shared__ float xs[RPB][K + 1];  // +1 pad: kill 8-way bank conflict (M=64 case)

    const int row0 = blockIdx.x * RPB;

    // cooperative stage of RPB input rows
    for (int i = threadIdx.x; i < RPB * K; i += 256) {
        int rr = i / K, kk = i - rr * K;
        int n = row0 + rr;
        float v = 0.f;
        if (n < N) {
            v = in[(size_t)n * LDIN + kk];
            if (RELU_IN) v = fmaxf(v, 0.f);
        }
        xs[rr][kk] = v;
    }
    __syncthreads();

    const int tr = threadIdx.x % TPR;
    const int rr = threadIdx.x / TPR;
    const int c  = tr * 8;
    const int n  = row0 + rr;
    if (n >= N) return;

    const size_t wbase = BASISW ? ((size_t)(c >> 6) * K * 64 + (c & 63))
                                : (size_t)c;

    float a0 = 0.f, a1 = 0.f, a2 = 0.f, a3 = 0.f;
    float a4 = 0.f, a5 = 0.f, a6 = 0.f, a7 = 0.f;
#pragma unroll 8
    for (int k = 0; k < K; ++k) {
        float xv = xs[rr][k];
        float4 w0 = *(const float4*)(W + wbase + (size_t)k * 64);
        float4 w1 = *(const float4*)(W + wbase + (size_t)k * 64 + 4);
        a0 = fmaf(xv, w0.x, a0); a1 = fmaf(xv, w0.y, a1);
        a2 = fmaf(xv, w0.z, a2); a3 = fmaf(xv, w0.w, a3);
        a4 = fmaf(xv, w1.x, a4); a5 = fmaf(xv, w1.y, a5);
        a6 = fmaf(xv, w1.z, a6); a7 = fmaf(xv, w1.w, a7);
    }
    if (HASBIAS) {
        a0 += bias[c + 0]; a1 += bias[c + 1]; a2 += bias[c + 2]; a3 += bias[c + 3];
        a4 += bias[c + 4]; a5 += bias[c + 5]; a6 += bias[c + 6]; a7 += bias[c + 7];
    }
    float* op = out + (size_t)n * LDOUT + c;
    *(float4*)(op)     = make_float4(a0, a1, a2, a3);
    *(float4*)(op + 4) = make_float4(a4, a5, a6, a7);
}

// ---------------------------------------------------------------------------
// Edge scatter: one 64-lane wave-slice per edge, lane = output channel.
//   msg[o] = sum_b comp[r,b] * h[src, b*64 + o]
//   out[dst, o] += msg[o] / cnt[dst, r]      (mean folded into per-edge scale)
// ---------------------------------------------------------------------------
template<int LDH, int LDO>
__global__ __launch_bounds__(256) void edge_kernel(const int* __restrict__ src,
                                                   const int* __restrict__ dst,
                                                   const int* __restrict__ et,
                                                   const int* __restrict__ cnt,
                                                   const float* __restrict__ comp,
                                                   const float* __restrict__ h,
                                                   float* __restrict__ out, int E)
{
    const int lane = threadIdx.x & 63;
    const int e = blockIdx.x * 4 + (threadIdx.x >> 6);
    if (e >= E) return;

    const int s = src[e];
    const int d = dst[e];
    const int r = et[e];

    const float c0 = comp[r * NBASE + 0];
    const float c1 = comp[r * NBASE + 1];
    const float c2 = comp[r * NBASE + 2];
    const float c3 = comp[r * NBASE + 3];

    int ncnt = cnt[d * NREL + r];
    const float inv = 1.0f / (float)(ncnt > 0 ? ncnt : 1);

    const float* hp = h + (size_t)s * LDH;
    float v = c0 * hp[lane]       + c1 * hp[64 + lane]
            + c2 * hp[128 + lane] + c3 * hp[192 + lane];

    unsafeAtomicAdd(out + (size_t)d * LDO + lane, v * inv);
}

// ---------------------------------------------------------------------------
extern "C" void kernel_launch(void* const* d_in, const int* in_sizes, int n_in,
                              void* d_out, int out_size, void* d_ws, size_t ws_size,
                              hipStream_t stream)
{
    const float* x      = (const float*)d_in[0];
    const int*   ei     = (const int*)d_in[1];   // [2, E]
    const int*   et     = (const int*)d_in[2];   // [E]
    const float* basis1 = (const float*)d_in[3]; // [4,128,64]
    const float* comp1  = (const float*)d_in[4]; // [8,4]
    const float* root1  = (const float*)d_in[5]; // [128,64]
    const float* bias1  = (const float*)d_in[6]; // [64]
    const float* basis2 = (const float*)d_in[7]; // [4,64,64]
    const float* comp2  = (const float*)d_in[8];
    const float* root2  = (const float*)d_in[9]; // [64,64]
    const float* bias2  = (const float*)d_in[10];
    float* out = (float*)d_out;

    const int N = in_sizes[0] / 128;
    const int E = in_sizes[2];
    const int* src  = ei;
    const int* dstp = ei + E;

    // workspace layout
    char* ws = (char*)d_ws;
    int* cnt = (int*)ws;                                   // N*8 ints
    size_t off = ((size_t)N * NREL * sizeof(int) + 255) & ~(size_t)255;
    float* buf1 = (float*)(ws + off);                      // [N, 320]
    // cols 0..255: basis projections (h), cols 256..319: conv output / x2

    hipMemsetAsync(cnt, 0, (size_t)N * NREL * sizeof(int), stream);
    count_kernel<<<(E + 255) / 256, 256, 0, stream>>>(dstp, et, cnt, E);

    // ---- layer 1 (in=128) ----
    gemm8<128, 256, 128, 320, false, false, true>
        <<<(N + 7) / 8, 256, 0, stream>>>(x, basis1, nullptr, buf1, N);
    gemm8<128, 64, 128, 320, false, true, false>
        <<<(N + 31) / 32, 256, 0, stream>>>(x, root1, bias1, buf1 + 256, N);
    edge_kernel<320, 320>
        <<<(E + 3) / 4, 256, 0, stream>>>(src, dstp, et, cnt, comp1, buf1, buf1 + 256, E);

    // ---- layer 2 (in=64, x2 = relu(buf1 cols 256..319)) ----
    gemm8<64, 256, 320, 320, true, false, true>
        <<<(N + 7) / 8, 256, 0, stream>>>(buf1 + 256, basis2, nullptr, buf1, N);
    gemm8<64, 64, 320, 64, true, true, false>
        <<<(N + 31) / 32, 256, 0, stream>>>(buf1 + 256, root2, bias2, out, N);
    edge_kernel<320, 64>
        <<<(E + 3) / 4, 256, 0, stream>>>(src, dstp, et, cnt, comp2, buf1, out, E);
}

// Round 2
// 308.031 us; speedup vs baseline: 2.0470x; 2.0470x over previous
//
#include <hip/hip_runtime.h>
#include <cstddef>

#define NREL 8

typedef __bf16 bf16x8 __attribute__((ext_vector_type(8)));
typedef float f32x4 __attribute__((ext_vector_type(4)));

__device__ __forceinline__ short f2bf(float f) {
    unsigned u = __float_as_uint(f);
    u += 0x7FFFu + ((u >> 16) & 1u);           // RNE
    return (short)(u >> 16);
}
__device__ __forceinline__ float bf_lo(int w) { return __uint_as_float((unsigned)w << 16); }
__device__ __forceinline__ float bf_hi(int w) { return __uint_as_float((unsigned)w & 0xffff0000u); }

// ---------------------------------------------------------------------------
// Histogram: deg[dst]++ and cnt8[dst*8+rel]++
// ---------------------------------------------------------------------------
__global__ __launch_bounds__(256) void hist_kernel(const int* __restrict__ dst,
                                                   const int* __restrict__ et,
                                                   int* __restrict__ deg,
                                                   int* __restrict__ cnt8, int E)
{
    int e = blockIdx.x * 256 + threadIdx.x;
    if (e >= E) return;
    int d = dst[e];
    atomicAdd(&deg[d], 1);
    atomicAdd(&cnt8[d * NREL + et[e]], 1);
}

// ---------------------------------------------------------------------------
// Single-block hierarchical exclusive scan of deg[N] -> offs[N+1]
// ---------------------------------------------------------------------------
__global__ __launch_bounds__(1024) void scan_kernel(const int* __restrict__ deg,
                                                    int* __restrict__ offs, int n)
{
    __shared__ int wsum[16];
    __shared__ int carry_s;
    const int tid = threadIdx.x, lane = tid & 63, wid = tid >> 6;
    if (tid == 0) carry_s = 0;
    __syncthreads();
    for (int base = 0; base < n; base += 1024) {
        int i = base + tid;
        int v = (i < n) ? deg[i] : 0;
        int s = v;
        for (int d = 1; d < 64; d <<= 1) {
            int t = __shfl_up(s, d, 64);
            if (lane >= d) s += t;
        }
        if (lane == 63) wsum[wid] = s;
        __syncthreads();
        if (wid == 0 && lane < 16) {
            int ws = wsum[lane];
            for (int d = 1; d < 16; d <<= 1) {
                int t = __shfl_up(ws, d, 64);
                if (lane >= d) ws += t;
            }
            wsum[lane] = ws;
        }
        __syncthreads();
        int prefix = carry_s + (wid > 0 ? wsum[wid - 1] : 0);
        if (i < n) offs[i] = prefix + s - v;   // exclusive
        __syncthreads();
        if (tid == 0) carry_s += wsum[15];
        __syncthreads();
    }
    if (threadIdx.x == 0) offs[n] = carry_s;
}

// ---------------------------------------------------------------------------
// inv8[i] = 1 / max(cnt8[i], 1)
// ---------------------------------------------------------------------------
__global__ __launch_bounds__(256) void inv_kernel(const int* __restrict__ cnt8,
                                                  float* __restrict__ inv8, int n8)
{
    int i = blockIdx.x * 256 + threadIdx.x;
    if (i < n8) inv8[i] = 1.0f / (float)(cnt8[i] > 1 ? cnt8[i] : 1);
}

// ---------------------------------------------------------------------------
// Scatter edges into dst-bucketed order. packedS = src | rel<<29, invE = 1/cnt.
// ---------------------------------------------------------------------------
__global__ __launch_bounds__(256) void scatter_kernel(const int* __restrict__ src,
                                                      const int* __restrict__ dst,
                                                      const int* __restrict__ et,
                                                      const int* __restrict__ offs,
                                                      int* __restrict__ cursor,
                                                      const float* __restrict__ inv8,
                                                      int* __restrict__ packedS,
                                                      float* __restrict__ invE, int E)
{
    int e = blockIdx.x * 256 + threadIdx.x;
    if (e >= E) return;
    int d = dst[e], r = et[e], s = src[e];
    int pos = offs[d] + atomicAdd(&cursor[d], 1);
    packedS[pos] = s | (r << 29);
    invE[pos] = inv8[d * NREL + r];
}

// ---------------------------------------------------------------------------
// Prepack W = [basis | root] transposed to bf16 Wt[320][K]
// ---------------------------------------------------------------------------
template<int K>
__global__ __launch_bounds__(256) void prepack_kernel(const float* __restrict__ basis,
                                                      const float* __restrict__ root,
                                                      short* __restrict__ Wt)
{
    int id = blockIdx.x * 256 + threadIdx.x;
    if (id >= 320 * K) return;
    int col = id / K, k = id - col * K;
    float v = (col < 256) ? basis[((col >> 6) * K + k) * 64 + (col & 63)]
                          : root[k * 64 + (col - 256)];
    Wt[id] = f2bf(v);
}

// ---------------------------------------------------------------------------
// Fused basis+root GEMM: [N,K] x [K,320] via mfma_f32_16x16x32_bf16.
// No LDS. 4 waves/block, wave w owns rows blk*64+w*16..+15, all 320 cols.
// Cols 0..255 -> h4[n][c][b] bf16 (b = col>>6, c = col&63); cols 256..319 ->
// yinit[n][64] f32 (+bias).
// ---------------------------------------------------------------------------
template<int K, bool ABF16>
__global__ __launch_bounds__(256) void gemm_mfma(const void* __restrict__ Ap,
                                                 const short* __restrict__ Wt,
                                                 const float* __restrict__ bias,
                                                 short* __restrict__ h4,
                                                 float* __restrict__ yinit, int N)
{
    constexpr int NK = K / 32;
    const int w = threadIdx.x >> 6, lane = threadIdx.x & 63;
    const int kg = lane >> 4, lr = lane & 15;
    const int arow = blockIdx.x * 64 + w * 16 + lr;
    const int ar = arow < N ? arow : N - 1;

    bf16x8 afrag[NK];
    if (ABF16) {
        const short* A = (const short*)Ap;
#pragma unroll
        for (int ks = 0; ks < NK; ++ks)
            afrag[ks] = *(const bf16x8*)(A + (size_t)ar * K + ks * 32 + kg * 8);
    } else {
        const float* A = (const float*)Ap;
#pragma unroll
        for (int ks = 0; ks < NK; ++ks) {
            const float* ap = A + (size_t)ar * K + ks * 32 + kg * 8;
            float4 u = *(const float4*)(ap);
            float4 v = *(const float4*)(ap + 4);
            union { short s[8]; bf16x8 v; } cv;
            cv.s[0] = f2bf(u.x); cv.s[1] = f2bf(u.y); cv.s[2] = f2bf(u.z); cv.s[3] = f2bf(u.w);
            cv.s[4] = f2bf(v.x); cv.s[5] = f2bf(v.y); cv.s[6] = f2bf(v.z); cv.s[7] = f2bf(v.w);
            afrag[ks] = cv.v;
        }
    }

    f32x4 acc[20];
#pragma unroll
    for (int t = 0; t < 20; ++t) acc[t] = (f32x4){0.f, 0.f, 0.f, 0.f};

#pragma unroll
    for (int t = 0; t < 20; ++t) {
        const short* bp = Wt + (size_t)(t * 16 + lr) * K + kg * 8;
#pragma unroll
        for (int ks = 0; ks < NK; ++ks) {
            bf16x8 bfrag = *(const bf16x8*)(bp + ks * 32);
            acc[t] = __builtin_amdgcn_mfma_f32_16x16x32_bf16(afrag[ks], bfrag, acc[t], 0, 0, 0);
        }
    }

    const int drow0 = blockIdx.x * 64 + w * 16 + kg * 4;
#pragma unroll
    for (int t = 0; t < 16; ++t) {
        int col = t * 16 + lr, b = col >> 6, c = col & 63;
#pragma unroll
        for (int r = 0; r < 4; ++r) {
            int dr = drow0 + r;
            if (dr < N) h4[(size_t)dr * 256 + c * 4 + b] = f2bf(acc[t][r]);
        }
    }
#pragma unroll
    for (int t = 16; t < 20; ++t) {
        int c = (t - 16) * 16 + lr;
        float bv = bias[c];
#pragma unroll
        for (int r = 0; r < 4; ++r) {
            int dr = drow0 + r;
            if (dr < N) yinit[(size_t)dr * 64 + c] = acc[t][r] + bv;
        }
    }
}

// ---------------------------------------------------------------------------
// Aggregate: one 64-lane slice per dst node, lane = channel. Register
// accumulation over the node's bucketed edges; one store per node.
// BF16OUT: store relu(acc) as bf16 (layer 1 -> x2); else f32 (layer 2 -> out).
// ---------------------------------------------------------------------------
template<bool BF16OUT>
__global__ __launch_bounds__(256) void agg_kernel(const int* __restrict__ offs,
                                                  const int* __restrict__ packedS,
                                                  const float* __restrict__ invE,
                                                  const float* __restrict__ comp,
                                                  const short* __restrict__ h4,
                                                  const float* __restrict__ init,
                                                  float* __restrict__ outF,
                                                  short* __restrict__ outB, int N)
{
    __shared__ float4 compS[NREL];
    if (threadIdx.x < NREL) compS[threadIdx.x] = ((const float4*)comp)[threadIdx.x];
    __syncthreads();

    const int dst = blockIdx.x * 4 + (threadIdx.x >> 6);
    const int c = threadIdx.x & 63;
    if (dst >= N) return;

    float acc = init[(size_t)dst * 64 + c];
    int e0 = offs[dst], e1 = offs[dst + 1];

    int e = e0;
    for (; e + 1 < e1; e += 2) {
        int p0 = packedS[e], p1 = packedS[e + 1];
        float i0 = invE[e], i1 = invE[e + 1];
        int s0 = p0 & 0x1FFFFFFF, s1 = p1 & 0x1FFFFFFF;
        float4 w0 = compS[(unsigned)p0 >> 29];
        float4 w1 = compS[(unsigned)p1 >> 29];
        int2 ha = *(const int2*)(h4 + (size_t)s0 * 256 + c * 4);
        int2 hb = *(const int2*)(h4 + (size_t)s1 * 256 + c * 4);
        acc += (w0.x * bf_lo(ha.x) + w0.y * bf_hi(ha.x) +
                w0.z * bf_lo(ha.y) + w0.w * bf_hi(ha.y)) * i0;
        acc += (w1.x * bf_lo(hb.x) + w1.y * bf_hi(hb.x) +
                w1.z * bf_lo(hb.y) + w1.w * bf_hi(hb.y)) * i1;
    }
    if (e < e1) {
        int p0 = packedS[e];
        float i0 = invE[e];
        int s0 = p0 & 0x1FFFFFFF;
        float4 w0 = compS[(unsigned)p0 >> 29];
        int2 ha = *(const int2*)(h4 + (size_t)s0 * 256 + c * 4);
        acc += (w0.x * bf_lo(ha.x) + w0.y * bf_hi(ha.x) +
                w0.z * bf_lo(ha.y) + w0.w * bf_hi(ha.y)) * i0;
    }

    if (BF16OUT) outB[(size_t)dst * 64 + c] = f2bf(fmaxf(acc, 0.f));
    else         outF[(size_t)dst * 64 + c] = acc;
}

// ---------------------------------------------------------------------------
extern "C" void kernel_launch(void* const* d_in, const int* in_sizes, int n_in,
                              void* d_out, int out_size, void* d_ws, size_t ws_size,
                              hipStream_t stream)
{
    const float* x      = (const float*)d_in[0];
    const int*   ei     = (const int*)d_in[1];
    const int*   et     = (const int*)d_in[2];
    const float* basis1 = (const float*)d_in[3];
    const float* comp1  = (const float*)d_in[4];
    const float* root1  = (const float*)d_in[5];
    const float* bias1  = (const float*)d_in[6];
    const float* basis2 = (const float*)d_in[7];
    const float* comp2  = (const float*)d_in[8];
    const float* root2  = (const float*)d_in[9];
    const float* bias2  = (const float*)d_in[10];
    float* out = (float*)d_out;

    const int N = in_sizes[0] / 128;
    const int E = in_sizes[2];
    const int* src  = ei;
    const int* dstp = ei + E;

    // -------- workspace carve (all 256B-aligned) --------
    char* p = (char*)d_ws;
    auto carve = [&](size_t bytes) -> char* {
        char* q = p; p += (bytes + 255) & ~(size_t)255; return q;
    };
    int*   deg     = (int*)carve((size_t)N * 4);          // zeroed
    int*   cursor  = (int*)carve((size_t)N * 4);          // zeroed
    int*   cnt8    = (int*)carve((size_t)N * NREL * 4);   // zeroed
    char*  zend    = p;
    int*   offs    = (int*)carve((size_t)(N + 1) * 4);
    float* inv8    = (float*)carve((size_t)N * NREL * 4);
    int*   packedS = (int*)carve((size_t)E * 4);
    float* invE    = (float*)carve((size_t)E * 4);
    short* Wt1     = (short*)carve((size_t)320 * 128 * 2);
    short* Wt2     = (short*)carve((size_t)320 * 64 * 2);
    float* y1init  = (float*)carve((size_t)N * 64 * 4);
    short* x2      = (short*)carve((size_t)N * 64 * 2);
    short* h4      = (short*)carve((size_t)N * 256 * 2);

    hipMemsetAsync(deg, 0, (size_t)(zend - (char*)deg), stream);

    // -------- edge bucketing (shared by both layers) --------
    hist_kernel<<<(E + 255) / 256, 256, 0, stream>>>(dstp, et, deg, cnt8, E);
    scan_kernel<<<1, 1024, 0, stream>>>(deg, offs, N);
    inv_kernel<<<(N * NREL + 255) / 256, 256, 0, stream>>>(cnt8, inv8, N * NREL);
    scatter_kernel<<<(E + 255) / 256, 256, 0, stream>>>(src, dstp, et, offs, cursor,
                                                        inv8, packedS, invE, E);

    // -------- weight prepack --------
    prepack_kernel<128><<<(320 * 128 + 255) / 256, 256, 0, stream>>>(basis1, root1, Wt1);
    prepack_kernel<64><<<(320 * 64 + 255) / 256, 256, 0, stream>>>(basis2, root2, Wt2);

    const int gblk = (N + 63) / 64;
    const int ablk = (N + 3) / 4;

    // -------- layer 1 --------
    gemm_mfma<128, false><<<gblk, 256, 0, stream>>>(x, Wt1, bias1, h4, y1init, N);
    agg_kernel<true><<<ablk, 256, 0, stream>>>(offs, packedS, invE, comp1, h4,
                                               y1init, nullptr, x2, N);

    // -------- layer 2 --------
    gemm_mfma<64, true><<<gblk, 256, 0, stream>>>(x2, Wt2, bias2, h4, out, N);
    agg_kernel<false><<<ablk, 256, 0, stream>>>(offs, packedS, invE, comp2, h4,
                                                out, out, nullptr, N);
}

// Round 3
// 241.650 us; speedup vs baseline: 2.6094x; 1.2747x over previous
//
#include <hip/hip_runtime.h>
#include <cstddef>

#define NREL 8
#define SCAN_TILE 4096

typedef __bf16 bf16x8 __attribute__((ext_vector_type(8)));
typedef float f32x4 __attribute__((ext_vector_type(4)));

__device__ __forceinline__ unsigned f2bf_u(float f) {
    unsigned u = __float_as_uint(f);
    u += 0x7FFFu + ((u >> 16) & 1u);           // RNE
    return u >> 16;
}
__device__ __forceinline__ short f2bf(float f) { return (short)f2bf_u(f); }
__device__ __forceinline__ int pack2bf(float lo, float hi) {
    return (int)(f2bf_u(lo) | (f2bf_u(hi) << 16));
}
__device__ __forceinline__ float bf_lo(int w) { return __uint_as_float((unsigned)w << 16); }
__device__ __forceinline__ float bf_hi(int w) { return __uint_as_float((unsigned)w & 0xffff0000u); }

// ---------------------------------------------------------------------------
// Histogram per (dst, relation): cnt8[dst*8+rel]++   (cnt8 pre-zeroed)
// ---------------------------------------------------------------------------
__global__ __launch_bounds__(256) void hist_kernel(const int* __restrict__ dst,
                                                   const int* __restrict__ et,
                                                   int* __restrict__ cnt8, int E)
{
    int e = blockIdx.x * 256 + threadIdx.x;
    if (e < E) atomicAdd(&cnt8[dst[e] * NREL + et[e]], 1);
}

// ---------------------------------------------------------------------------
// Scan stage 1: per-tile degree sums (deg[n] = sum_r cnt8[n*8+r])
// ---------------------------------------------------------------------------
__global__ __launch_bounds__(256) void scan_part(const int* __restrict__ cnt8,
                                                 int* __restrict__ tsum, int n)
{
    int base = blockIdx.x * SCAN_TILE;
    int s = 0;
    for (int i = threadIdx.x; i < SCAN_TILE; i += 256) {
        int idx = base + i;
        if (idx < n) {
            int4 a = ((const int4*)cnt8)[idx * 2];
            int4 b = ((const int4*)cnt8)[idx * 2 + 1];
            s += a.x + a.y + a.z + a.w + b.x + b.y + b.z + b.w;
        }
    }
    for (int d = 1; d < 64; d <<= 1) s += __shfl_xor(s, d, 64);
    __shared__ int ws[4];
    if ((threadIdx.x & 63) == 0) ws[threadIdx.x >> 6] = s;
    __syncthreads();
    if (threadIdx.x == 0) tsum[blockIdx.x] = ws[0] + ws[1] + ws[2] + ws[3];
}

// ---------------------------------------------------------------------------
// Scan stage 2: serial exclusive scan of tile sums (nt <= ~64), total -> offs_n
// ---------------------------------------------------------------------------
__global__ void scan_mid(int* __restrict__ tsum, int* __restrict__ offs_n, int nt)
{
    if (threadIdx.x == 0) {
        int run = 0;
        for (int i = 0; i < nt; ++i) { int t = tsum[i]; tsum[i] = run; run += t; }
        *offs_n = run;
    }
}

// ---------------------------------------------------------------------------
// Scan stage 3: per-tile exclusive scan + tile offset -> offs[n]
// block = 256 threads x 16 nodes each = SCAN_TILE nodes
// ---------------------------------------------------------------------------
__global__ __launch_bounds__(256) void scan_final(const int* __restrict__ cnt8,
                                                  const int* __restrict__ tsum,
                                                  int* __restrict__ offs, int n)
{
    const int lane = threadIdx.x & 63, wid = threadIdx.x >> 6;
    int base = blockIdx.x * SCAN_TILE + threadIdx.x * 16;
    int v[16]; int s = 0;
#pragma unroll
    for (int j = 0; j < 16; ++j) {
        int idx = base + j;
        int dv = 0;
        if (idx < n) {
            int4 a = ((const int4*)cnt8)[idx * 2];
            int4 b = ((const int4*)cnt8)[idx * 2 + 1];
            dv = a.x + a.y + a.z + a.w + b.x + b.y + b.z + b.w;
        }
        v[j] = dv; s += dv;
    }
    int inc = s;
    for (int d = 1; d < 64; d <<= 1) {
        int t = __shfl_up(inc, d, 64);
        if (lane >= d) inc += t;
    }
    __shared__ int wsum[4];
    if (lane == 63) wsum[wid] = inc;
    __syncthreads();
    int run = tsum[blockIdx.x] + (inc - s);
    for (int k = 0; k < wid; ++k) run += wsum[k];
#pragma unroll
    for (int j = 0; j < 16; ++j) {
        int idx = base + j;
        if (idx < n) offs[idx] = run;
        run += v[j];
    }
}

// ---------------------------------------------------------------------------
// Scatter edges into dst-bucketed order; edgeP = {src|rel<<29, bits(1/cnt)}
// ---------------------------------------------------------------------------
__global__ __launch_bounds__(256) void scatter_kernel(const int* __restrict__ src,
                                                      const int* __restrict__ dst,
                                                      const int* __restrict__ et,
                                                      const int* __restrict__ offs,
                                                      int* __restrict__ cursor,
                                                      const int* __restrict__ cnt8,
                                                      int2* __restrict__ edgeP, int E)
{
    int e = blockIdx.x * 256 + threadIdx.x;
    if (e >= E) return;
    int d = dst[e], r = et[e], s = src[e];
    int c = cnt8[d * NREL + r];
    float inv = 1.0f / (float)(c > 1 ? c : 1);
    int pos = offs[d] + atomicAdd(&cursor[d], 1);
    edgeP[pos] = make_int2(s | (r << 29), __float_as_int(inv));
}

// ---------------------------------------------------------------------------
// Prepack W = [basis | root] transposed to bf16 Wt[320][K]
// ---------------------------------------------------------------------------
template<int K>
__global__ __launch_bounds__(256) void prepack_kernel(const float* __restrict__ basis,
                                                      const float* __restrict__ root,
                                                      short* __restrict__ Wt)
{
    int id = blockIdx.x * 256 + threadIdx.x;
    if (id >= 320 * K) return;
    int col = id / K, k = id - col * K;
    float v = (col < 256) ? basis[((col >> 6) * K + k) * 64 + (col & 63)]
                          : root[k * 64 + (col - 256)];
    Wt[id] = f2bf(v);
}

// ---------------------------------------------------------------------------
// Fused basis+root GEMM: [N,K] x [K,320] via mfma_f32_16x16x32_bf16.
// Wave w owns rows blk*64+w*16..+15. Cols 0..255 -> h4[n][c][b] bf16 packed
// int2 stores (thread (kg,lr) holds all 4 b-values of col c4*16+lr in
// acc[c4+4b][r]); cols 256..319 -> yinit[n][64] f32 (+bias).
// ---------------------------------------------------------------------------
template<int K, bool ABF16>
__global__ __launch_bounds__(256) void gemm_mfma(const void* __restrict__ Ap,
                                                 const short* __restrict__ Wt,
                                                 const float* __restrict__ bias,
                                                 short* __restrict__ h4,
                                                 float* __restrict__ yinit, int N)
{
    constexpr int NK = K / 32;
    const int w = threadIdx.x >> 6, lane = threadIdx.x & 63;
    const int kg = lane >> 4, lr = lane & 15;
    const int arow = blockIdx.x * 64 + w * 16 + lr;
    const int ar = arow < N ? arow : N - 1;

    bf16x8 afrag[NK];
    if (ABF16) {
        const short* A = (const short*)Ap;
#pragma unroll
        for (int ks = 0; ks < NK; ++ks)
            afrag[ks] = *(const bf16x8*)(A + (size_t)ar * K + ks * 32 + kg * 8);
    } else {
        const float* A = (const float*)Ap;
#pragma unroll
        for (int ks = 0; ks < NK; ++ks) {
            const float* ap = A + (size_t)ar * K + ks * 32 + kg * 8;
            float4 u = *(const float4*)(ap);
            float4 v = *(const float4*)(ap + 4);
            union { short s[8]; bf16x8 v; } cv;
            cv.s[0] = f2bf(u.x); cv.s[1] = f2bf(u.y); cv.s[2] = f2bf(u.z); cv.s[3] = f2bf(u.w);
            cv.s[4] = f2bf(v.x); cv.s[5] = f2bf(v.y); cv.s[6] = f2bf(v.z); cv.s[7] = f2bf(v.w);
            afrag[ks] = cv.v;
        }
    }

    f32x4 acc[20];
#pragma unroll
    for (int t = 0; t < 20; ++t) acc[t] = (f32x4){0.f, 0.f, 0.f, 0.f};

#pragma unroll
    for (int t = 0; t < 20; ++t) {
        const short* bp = Wt + (size_t)(t * 16 + lr) * K + kg * 8;
#pragma unroll
        for (int ks = 0; ks < NK; ++ks) {
            bf16x8 bfrag = *(const bf16x8*)(bp + ks * 32);
            acc[t] = __builtin_amdgcn_mfma_f32_16x16x32_bf16(afrag[ks], bfrag, acc[t], 0, 0, 0);
        }
    }

    const int drow0 = blockIdx.x * 64 + w * 16 + kg * 4;
#pragma unroll
    for (int r = 0; r < 4; ++r) {
        int dr = drow0 + r;
        if (dr >= N) break;
#pragma unroll
        for (int c4 = 0; c4 < 4; ++c4) {
            int u0 = pack2bf(acc[c4][r],     acc[c4 + 4][r]);
            int u1 = pack2bf(acc[c4 + 8][r], acc[c4 + 12][r]);
            *(int2*)(h4 + (size_t)dr * 256 + (c4 * 16 + lr) * 4) = make_int2(u0, u1);
        }
#pragma unroll
        for (int t = 16; t < 20; ++t) {
            int c = (t - 16) * 16 + lr;
            yinit[(size_t)dr * 64 + c] = acc[t][r] + bias[c];
        }
    }
}

// ---------------------------------------------------------------------------
// Aggregate: one 64-lane slice per dst node, lane = channel. Register
// accumulation over the node's bucketed edges; one store per node.
// ---------------------------------------------------------------------------
template<bool BF16OUT>
__global__ __launch_bounds__(256) void agg_kernel(const int* __restrict__ offs,
                                                  const int2* __restrict__ edgeP,
                                                  const float* __restrict__ comp,
                                                  const short* __restrict__ h4,
                                                  const float* __restrict__ init,
                                                  float* __restrict__ outF,
                                                  short* __restrict__ outB, int N)
{
    __shared__ float4 compS[NREL];
    if (threadIdx.x < NREL) compS[threadIdx.x] = ((const float4*)comp)[threadIdx.x];
    __syncthreads();

    const int dst = blockIdx.x * 4 + (threadIdx.x >> 6);
    const int c = threadIdx.x & 63;
    if (dst >= N) return;

    float acc = init[(size_t)dst * 64 + c];
    int e0 = offs[dst], e1 = offs[dst + 1];

    int e = e0;
    for (; e + 1 < e1; e += 2) {
        int2 pa = edgeP[e], pb = edgeP[e + 1];
        float i0 = __int_as_float(pa.y), i1 = __int_as_float(pb.y);
        int s0 = pa.x & 0x1FFFFFFF, s1 = pb.x & 0x1FFFFFFF;
        float4 w0 = compS[(unsigned)pa.x >> 29];
        float4 w1 = compS[(unsigned)pb.x >> 29];
        int2 ha = *(const int2*)(h4 + (size_t)s0 * 256 + c * 4);
        int2 hb = *(const int2*)(h4 + (size_t)s1 * 256 + c * 4);
        acc += (w0.x * bf_lo(ha.x) + w0.y * bf_hi(ha.x) +
                w0.z * bf_lo(ha.y) + w0.w * bf_hi(ha.y)) * i0;
        acc += (w1.x * bf_lo(hb.x) + w1.y * bf_hi(hb.x) +
                w1.z * bf_lo(hb.y) + w1.w * bf_hi(hb.y)) * i1;
    }
    if (e < e1) {
        int2 pa = edgeP[e];
        float i0 = __int_as_float(pa.y);
        int s0 = pa.x & 0x1FFFFFFF;
        float4 w0 = compS[(unsigned)pa.x >> 29];
        int2 ha = *(const int2*)(h4 + (size_t)s0 * 256 + c * 4);
        acc += (w0.x * bf_lo(ha.x) + w0.y * bf_hi(ha.x) +
                w0.z * bf_lo(ha.y) + w0.w * bf_hi(ha.y)) * i0;
    }

    if (BF16OUT) outB[(size_t)dst * 64 + c] = f2bf(fmaxf(acc, 0.f));
    else         outF[(size_t)dst * 64 + c] = acc;
}

// ---------------------------------------------------------------------------
extern "C" void kernel_launch(void* const* d_in, const int* in_sizes, int n_in,
                              void* d_out, int out_size, void* d_ws, size_t ws_size,
                              hipStream_t stream)
{
    const float* x      = (const float*)d_in[0];
    const int*   ei     = (const int*)d_in[1];
    const int*   et     = (const int*)d_in[2];
    const float* basis1 = (const float*)d_in[3];
    const float* comp1  = (const float*)d_in[4];
    const float* root1  = (const float*)d_in[5];
    const float* bias1  = (const float*)d_in[6];
    const float* basis2 = (const float*)d_in[7];
    const float* comp2  = (const float*)d_in[8];
    const float* root2  = (const float*)d_in[9];
    const float* bias2  = (const float*)d_in[10];
    float* out = (float*)d_out;

    const int N = in_sizes[0] / 128;
    const int E = in_sizes[2];
    const int* src  = ei;
    const int* dstp = ei + E;

    // -------- workspace carve (256B aligned) --------
    char* p = (char*)d_ws;
    auto carve = [&](size_t bytes) -> char* {
        char* q = p; p += (bytes + 255) & ~(size_t)255; return q;
    };
    int*   cursor  = (int*)carve((size_t)N * 4);          // zeroed
    int*   cnt8    = (int*)carve((size_t)N * NREL * 4);   // zeroed
    char*  zend    = p;
    int*   offs    = (int*)carve((size_t)(N + 1) * 4);
    int*   tsum    = (int*)carve(256 * 4);
    int2*  edgeP   = (int2*)carve((size_t)E * 8);
    short* Wt1     = (short*)carve((size_t)320 * 128 * 2);
    short* Wt2     = (short*)carve((size_t)320 * 64 * 2);
    float* y1init  = (float*)carve((size_t)N * 64 * 4);
    short* x2      = (short*)carve((size_t)N * 64 * 2);
    short* h4      = (short*)carve((size_t)N * 256 * 2);

    hipMemsetAsync(cursor, 0, (size_t)(zend - (char*)cursor), stream);

    const int ntiles = (N + SCAN_TILE - 1) / SCAN_TILE;

    // -------- edge bucketing (shared by both layers) --------
    hist_kernel<<<(E + 255) / 256, 256, 0, stream>>>(dstp, et, cnt8, E);
    scan_part<<<ntiles, 256, 0, stream>>>(cnt8, tsum, N);
    scan_mid<<<1, 64, 0, stream>>>(tsum, offs + N, ntiles);
    scan_final<<<ntiles, 256, 0, stream>>>(cnt8, tsum, offs, N);
    scatter_kernel<<<(E + 255) / 256, 256, 0, stream>>>(src, dstp, et, offs, cursor,
                                                        cnt8, edgeP, E);

    // -------- weight prepack --------
    prepack_kernel<128><<<(320 * 128 + 255) / 256, 256, 0, stream>>>(basis1, root1, Wt1);
    prepack_kernel<64><<<(320 * 64 + 255) / 256, 256, 0, stream>>>(basis2, root2, Wt2);

    const int gblk = (N + 63) / 64;
    const int ablk = (N + 3) / 4;

    // -------- layer 1 --------
    gemm_mfma<128, false><<<gblk, 256, 0, stream>>>(x, Wt1, bias1, h4, y1init, N);
    agg_kernel<true><<<ablk, 256, 0, stream>>>(offs, edgeP, comp1, h4, y1init,
                                               nullptr, x2, N);

    // -------- layer 2 --------
    gemm_mfma<64, true><<<gblk, 256, 0, stream>>>(x2, Wt2, bias2, h4, out, N);
    agg_kernel<false><<<ablk, 256, 0, stream>>>(offs, edgeP, comp2, h4, out,
                                                out, nullptr, N);
}